// Round 1
// baseline (1053.179 us; speedup 1.0000x reference)
//
#include <hip/hip_runtime.h>

// ---------------------------------------------------------------------------
// SpatialAwareSelfAttention  (B=16, H=W=56, C=512, heads=8, window=4x4)
//
// Round 0: correctness-first bf16-MFMA pipeline.
//   K0a: weights fp32 -> bf16 (w_qkv_h, wl_v = v-rows of w_qkv_l, wp1/wp2)
//   K0b: window partition x -> XW bf16 + window-mean XAVG bf16
//   K1a: VL = XAVG @ WLV^T            (bf16 out)
//   K1b: G  = VL @ WP2^T + b_proj     (fp32 out)  [global branch: softmax(1)=1]
//   K2 : fused qkv + window attention -> XH bf16  (block = 4 windows x 1 head)
//   K3 : out = XH @ WP1^T + G[win], window-reverse scatter (fp32)
// ---------------------------------------------------------------------------

using bf16x8 = __attribute__((ext_vector_type(8))) short;
using f32x4  = __attribute__((ext_vector_type(4))) float;

#define NWIN  3136      // 16 * 14 * 14
#define NTOK  50176     // NWIN * 16
#define SCALE 0.044194173824159216f   // 512^-0.5 (full C, per reference)

__device__ __forceinline__ unsigned short f2bf(float f) {
    union { float f; unsigned u; } v; v.f = f;
    unsigned u = v.u;
    return (unsigned short)((u + 0x7fffu + ((u >> 16) & 1u)) >> 16);
}

// ---- K0a: weight conversion/repack ----------------------------------------
__global__ void k_prep_weights(const float* __restrict__ wqkv_h,
                               const float* __restrict__ wqkv_l,
                               const float* __restrict__ wproj,
                               unsigned short* __restrict__ WH,
                               unsigned short* __restrict__ WLV,
                               unsigned short* __restrict__ WP1,
                               unsigned short* __restrict__ WP2) {
    int i = blockIdx.x * 256 + threadIdx.x;   // total = 1536*512 + 3*512*512
    if (i < 786432) {
        WH[i] = f2bf(wqkv_h[i]);              // [1536][512] row-major, K contig
    } else {
        int j = i - 786432;
        int r = j >> 18;                      // / 262144
        int t = j & 262143;
        int n = t >> 9, k = t & 511;
        if (r == 0)      WLV[t] = f2bf(wqkv_l[(1024 + n) * 512 + k]); // v-rows
        else if (r == 1) WP1[t] = f2bf(wproj[n * 1024 + k]);          // cols 0:512
        else             WP2[t] = f2bf(wproj[n * 1024 + 512 + k]);    // cols 512:1024
    }
}

// ---- K0b: window partition + pooling --------------------------------------
__global__ void k_window_pool(const float* __restrict__ x,
                              unsigned short* __restrict__ XW,
                              unsigned short* __restrict__ XAVG) {
    int win = blockIdx.x;
    int b = win / 196, rem = win % 196, wh = rem / 14, ww = rem % 14;
    int tid = threadIdx.x;
    for (int half = 0; half < 2; ++half) {
        int c = tid + half * 256;
        float s = 0.f;
        #pragma unroll
        for (int t = 0; t < 16; ++t) {
            int row = (b * 56 + wh * 4 + (t >> 2)) * 56 + ww * 4 + (t & 3);
            float v = x[row * 512 + c];
            XW[(win * 16 + t) * 512 + c] = f2bf(v);
            s += v;
        }
        XAVG[win * 512 + c] = f2bf(s * 0.0625f);
    }
}

// ---- K1: generic K=512 GEMM C = A @ B^T (wave tile 16x128) ----------------
__global__ void k_gemm512(const unsigned short* __restrict__ A,
                          const unsigned short* __restrict__ Bw,
                          unsigned short* __restrict__ outB,
                          float* __restrict__ outF,
                          const float* __restrict__ bias) {
    int wave = threadIdx.x >> 6, lane = threadIdx.x & 63;
    int quad = lane >> 4, l16 = lane & 15;
    int m0 = blockIdx.x * 64 + wave * 16;
    int n0 = blockIdx.y * 128;
    f32x4 acc[8] = {};
    const unsigned short* arow = A + (m0 + l16) * 512 + quad * 8;
    for (int kk = 0; kk < 16; ++kk) {
        bf16x8 a = *(const bf16x8*)(arow + kk * 32);
        #pragma unroll
        for (int nt = 0; nt < 8; ++nt) {
            bf16x8 b = *(const bf16x8*)(Bw + (n0 + nt * 16 + l16) * 512 + kk * 32 + quad * 8);
            acc[nt] = __builtin_amdgcn_mfma_f32_16x16x32_bf16(a, b, acc[nt], 0, 0, 0);
        }
    }
    #pragma unroll
    for (int nt = 0; nt < 8; ++nt) {
        int col = n0 + nt * 16 + l16;
        float bv = (bias != nullptr) ? bias[col] : 0.f;
        #pragma unroll
        for (int r = 0; r < 4; ++r) {
            int row = m0 + quad * 4 + r;
            if (outF != nullptr) outF[row * 512 + col] = acc[nt][r] + bv;
            else                 outB[row * 512 + col] = f2bf(acc[nt][r]);
        }
    }
}

// ---- K2: fused qkv + window attention -------------------------------------
// grid (784, 8): blockIdx.x = window group of 4, blockIdx.y = head.
// wave w handles window blockIdx.x*4 + w entirely for this head.
__global__ void __launch_bounds__(256) k_qkv_attn(const unsigned short* __restrict__ XW,
                                                  const unsigned short* __restrict__ WH,
                                                  unsigned short* __restrict__ XH) {
    __shared__ __align__(16) unsigned short q_s[4][16][64];
    __shared__ __align__(16) unsigned short k_s[4][16][64];
    __shared__ __align__(16) unsigned short vT_s[4][64][32];   // cols 16..31 zero pad
    __shared__ __align__(16) float          S_s[4][16][17];
    __shared__ __align__(16) unsigned short P_s[4][16][32];    // cols 16..31 zero pad

    int wave = threadIdx.x >> 6, lane = threadIdx.x & 63;
    int quad = lane >> 4, l16 = lane & 15;
    int head = blockIdx.y;
    int win  = blockIdx.x * 4 + wave;

    // zero the K-padding regions (K=16 padded to 32 for the P@V mfma)
    for (int idx = lane; idx < 64 * 16; idx += 64)
        vT_s[wave][idx >> 4][16 + (idx & 15)] = 0;
    for (int idx = lane; idx < 16 * 16; idx += 64)
        P_s[wave][idx >> 4][16 + (idx & 15)] = 0;

    // ---- phase 1: qkv = xw @ WH^T for this head's 192 cols -----------------
    f32x4 acc[12] = {};   // [s*4+nt], s=0:q 1:k 2:v, nt = 16-col subtile
    const unsigned short* arow = XW + (win * 16 + l16) * 512 + quad * 8;
    for (int kk = 0; kk < 16; ++kk) {
        bf16x8 a = *(const bf16x8*)(arow + kk * 32);
        #pragma unroll
        for (int s = 0; s < 3; ++s) {
            #pragma unroll
            for (int nt = 0; nt < 4; ++nt) {
                int nrow = s * 512 + head * 64 + nt * 16 + l16;
                bf16x8 b = *(const bf16x8*)(WH + nrow * 512 + kk * 32 + quad * 8);
                acc[s * 4 + nt] =
                    __builtin_amdgcn_mfma_f32_16x16x32_bf16(a, b, acc[s * 4 + nt], 0, 0, 0);
            }
        }
    }
    // C layout: row(token) = quad*4+r, col(ch) = nt*16 + l16
    #pragma unroll
    for (int nt = 0; nt < 4; ++nt) {
        #pragma unroll
        for (int r = 0; r < 4; ++r) {
            int tok = quad * 4 + r;
            q_s[wave][tok][nt * 16 + l16] = f2bf(acc[0 * 4 + nt][r]);
            k_s[wave][tok][nt * 16 + l16] = f2bf(acc[1 * 4 + nt][r]);
            vT_s[wave][nt * 16 + l16][tok] = f2bf(acc[2 * 4 + nt][r]);  // transposed
        }
    }
    __syncthreads();

    // ---- phase 2: S = (q @ k^T) * scale ------------------------------------
    f32x4 sacc = {};
    {
        bf16x8 a0 = *(const bf16x8*)&q_s[wave][l16][quad * 8];
        bf16x8 b0 = *(const bf16x8*)&k_s[wave][l16][quad * 8];
        sacc = __builtin_amdgcn_mfma_f32_16x16x32_bf16(a0, b0, sacc, 0, 0, 0);
        bf16x8 a1 = *(const bf16x8*)&q_s[wave][l16][32 + quad * 8];
        bf16x8 b1 = *(const bf16x8*)&k_s[wave][l16][32 + quad * 8];
        sacc = __builtin_amdgcn_mfma_f32_16x16x32_bf16(a1, b1, sacc, 0, 0, 0);
    }
    #pragma unroll
    for (int r = 0; r < 4; ++r)
        S_s[wave][quad * 4 + r][l16] = sacc[r] * SCALE;
    __syncthreads();

    // ---- phase 3: row softmax (16 rows, lanes 0..15) -----------------------
    if (lane < 16) {
        float vals[16], m = -1e30f;
        #pragma unroll
        for (int c = 0; c < 16; ++c) { vals[c] = S_s[wave][lane][c]; m = fmaxf(m, vals[c]); }
        float sum = 0.f;
        #pragma unroll
        for (int c = 0; c < 16; ++c) { vals[c] = __expf(vals[c] - m); sum += vals[c]; }
        float inv = 1.f / sum;
        #pragma unroll
        for (int c = 0; c < 16; ++c) P_s[wave][lane][c] = f2bf(vals[c] * inv);
    }
    __syncthreads();

    // ---- phase 4: y = P @ v  (K=16 padded to 32) ---------------------------
    bf16x8 ap = *(const bf16x8*)&P_s[wave][l16][quad * 8];
    #pragma unroll
    for (int nt = 0; nt < 4; ++nt) {
        f32x4 y = {};
        bf16x8 bv = *(const bf16x8*)&vT_s[wave][nt * 16 + l16][quad * 8];
        y = __builtin_amdgcn_mfma_f32_16x16x32_bf16(ap, bv, y, 0, 0, 0);
        #pragma unroll
        for (int r = 0; r < 4; ++r) {
            int tok = quad * 4 + r;
            XH[(win * 16 + tok) * 512 + head * 64 + nt * 16 + l16] = f2bf(y[r]);
        }
    }
}

// ---- K3: out = XH @ WP1^T + G[win], window-reverse scatter ----------------
__global__ void k_proj_out(const unsigned short* __restrict__ XH,
                           const unsigned short* __restrict__ WP1,
                           const float* __restrict__ G,
                           float* __restrict__ out) {
    int wave = threadIdx.x >> 6, lane = threadIdx.x & 63;
    int quad = lane >> 4, l16 = lane & 15;
    int win = blockIdx.x * 4 + wave;
    int n0  = blockIdx.y * 128;
    f32x4 acc[8] = {};
    const unsigned short* arow = XH + (win * 16 + l16) * 512 + quad * 8;
    for (int kk = 0; kk < 16; ++kk) {
        bf16x8 a = *(const bf16x8*)(arow + kk * 32);
        #pragma unroll
        for (int nt = 0; nt < 8; ++nt) {
            bf16x8 b = *(const bf16x8*)(WP1 + (n0 + nt * 16 + l16) * 512 + kk * 32 + quad * 8);
            acc[nt] = __builtin_amdgcn_mfma_f32_16x16x32_bf16(a, b, acc[nt], 0, 0, 0);
        }
    }
    int b = win / 196, rem = win % 196, wh = rem / 14, ww = rem % 14;
    #pragma unroll
    for (int nt = 0; nt < 8; ++nt) {
        int col = n0 + nt * 16 + l16;
        float gv = G[win * 512 + col];
        #pragma unroll
        for (int r = 0; r < 4; ++r) {
            int tok = quad * 4 + r;
            int row = (b * 56 + wh * 4 + (tok >> 2)) * 56 + ww * 4 + (tok & 3);
            out[row * 512 + col] = acc[nt][r] + gv;
        }
    }
}

// ---------------------------------------------------------------------------
extern "C" void kernel_launch(void* const* d_in, const int* in_sizes, int n_in,
                              void* d_out, int out_size, void* d_ws, size_t ws_size,
                              hipStream_t stream) {
    const float* x      = (const float*)d_in[0];
    const float* wqkv_h = (const float*)d_in[1];
    const float* wqkv_l = (const float*)d_in[2];
    const float* wproj  = (const float*)d_in[3];
    const float* bproj  = (const float*)d_in[4];
    float* out = (float*)d_out;

    char* ws = (char*)d_ws;
    // ws layout (bytes); total ~113 MB
    unsigned short* WH   = (unsigned short*)(ws + 0);         // 1536*512 bf16
    unsigned short* WLV  = (unsigned short*)(ws + 1572864);   // 512*512
    unsigned short* WP1  = (unsigned short*)(ws + 2097152);   // 512*512
    unsigned short* WP2  = (unsigned short*)(ws + 2621440);   // 512*512
    unsigned short* XW   = (unsigned short*)(ws + 3145728);   // 50176*512
    unsigned short* XAVG = (unsigned short*)(ws + 54525952);  // 3136*512
    unsigned short* VL   = (unsigned short*)(ws + 57737216);  // 3136*512
    float*          G    = (float*)(ws + 60948480);           // 3136*512 f32
    unsigned short* XH   = (unsigned short*)(ws + 67371008);  // 50176*512

    hipLaunchKernelGGL(k_prep_weights, dim3(6144), dim3(256), 0, stream,
                       wqkv_h, wqkv_l, wproj, WH, WLV, WP1, WP2);
    hipLaunchKernelGGL(k_window_pool, dim3(3136), dim3(256), 0, stream, x, XW, XAVG);
    hipLaunchKernelGGL(k_gemm512, dim3(49, 4), dim3(256), 0, stream,
                       XAVG, WLV, VL, (float*)nullptr, (const float*)nullptr);
    hipLaunchKernelGGL(k_gemm512, dim3(49, 4), dim3(256), 0, stream,
                       VL, WP2, (unsigned short*)nullptr, G, bproj);
    hipLaunchKernelGGL(k_qkv_attn, dim3(784, 8), dim3(256), 0, stream, XW, WH, XH);
    hipLaunchKernelGGL(k_proj_out, dim3(784, 4), dim3(256), 0, stream, XH, WP1, G, out);
}

// Round 2
// 539.891 us; speedup vs baseline: 1.9507x; 1.9507x over previous
//
#include <hip/hip_runtime.h>

// ---------------------------------------------------------------------------
// SpatialAwareSelfAttention  (B=16, H=W=56, C=512, heads=8, window=4x4)
//
// Round 1: m97-style tiled GEMMs with async global->LDS staging.
//   K0a: weights fp32 -> bf16
//   K0b: window partition x -> XW bf16 + window-mean XAVG bf16
//   K1 : VL = XAVG @ WLV^T ; G = VL @ WP2^T + b_proj   (small, wide grid)
//   K2 : k_fused: per (128-token block, head): qkv GEMM (LDS-staged) +
//        in-LDS window attention -> XH bf16
//   K3 : k_gemm_proj: out = XH @ WP1^T + G[win], window-reverse scatter
// ---------------------------------------------------------------------------

using bf16x8 = __attribute__((ext_vector_type(8))) short;
using f32x4  = __attribute__((ext_vector_type(4))) float;

#define SCALE 0.044194173824159216f   // 512^-0.5 (full C, per reference)

__device__ __forceinline__ unsigned short f2bf(float f) {
    union { float f; unsigned u; } v; v.f = f;
    unsigned u = v.u;
    return (unsigned short)((u + 0x7fffu + ((u >> 16) & 1u)) >> 16);
}

// async 16B global -> LDS (lds dest = wave-uniform base + lane*16)
__device__ __forceinline__ void gl2lds16(const unsigned short* g, unsigned short* l) {
    __builtin_amdgcn_global_load_lds(
        (const __attribute__((address_space(1))) void*)g,
        (__attribute__((address_space(3))) void*)l, 16, 0, 0);
}

// ---- K0a: weight conversion/repack ----------------------------------------
__global__ void k_prep_weights(const float* __restrict__ wqkv_h,
                               const float* __restrict__ wqkv_l,
                               const float* __restrict__ wproj,
                               unsigned short* __restrict__ WH,
                               unsigned short* __restrict__ WLV,
                               unsigned short* __restrict__ WP1,
                               unsigned short* __restrict__ WP2) {
    int i = blockIdx.x * 256 + threadIdx.x;
    if (i < 786432) {
        WH[i] = f2bf(wqkv_h[i]);              // [1536][512] row-major
    } else {
        int j = i - 786432;
        int r = j >> 18;
        int t = j & 262143;
        int n = t >> 9, k = t & 511;
        if (r == 0)      WLV[t] = f2bf(wqkv_l[(1024 + n) * 512 + k]); // v-rows
        else if (r == 1) WP1[t] = f2bf(wproj[n * 1024 + k]);
        else             WP2[t] = f2bf(wproj[n * 1024 + 512 + k]);
    }
}

// ---- K0b: window partition + pooling --------------------------------------
__global__ void k_window_pool(const float* __restrict__ x,
                              unsigned short* __restrict__ XW,
                              unsigned short* __restrict__ XAVG) {
    int win = blockIdx.x;
    int b = win / 196, rem = win % 196, wh = rem / 14, ww = rem % 14;
    int tid = threadIdx.x;
    for (int half = 0; half < 2; ++half) {
        int c = tid + half * 256;
        float s = 0.f;
        #pragma unroll
        for (int t = 0; t < 16; ++t) {
            int row = (b * 56 + wh * 4 + (t >> 2)) * 56 + ww * 4 + (t & 3);
            float v = x[(size_t)row * 512 + c];
            XW[(size_t)(win * 16 + t) * 512 + c] = f2bf(v);
            s += v;
        }
        XAVG[(size_t)win * 512 + c] = f2bf(s * 0.0625f);
    }
}

// ---- K1: small K=512 GEMM C = A @ B^T, wave tile 16 x (NT*16) -------------
template <int NT>
__global__ void k_gemm512(const unsigned short* __restrict__ A,
                          const unsigned short* __restrict__ Bw,
                          unsigned short* __restrict__ outB,
                          float* __restrict__ outF,
                          const float* __restrict__ bias) {
    int wave = threadIdx.x >> 6, lane = threadIdx.x & 63;
    int quad = lane >> 4, l16 = lane & 15;
    int m0 = blockIdx.x * 64 + wave * 16;
    int n0 = blockIdx.y * (NT * 16);
    f32x4 acc[NT] = {};
    const unsigned short* arow = A + (size_t)(m0 + l16) * 512 + quad * 8;
    for (int kk = 0; kk < 16; ++kk) {
        bf16x8 a = *(const bf16x8*)(arow + kk * 32);
        #pragma unroll
        for (int nt = 0; nt < NT; ++nt) {
            bf16x8 b = *(const bf16x8*)(Bw + (size_t)(n0 + nt * 16 + l16) * 512 + kk * 32 + quad * 8);
            acc[nt] = __builtin_amdgcn_mfma_f32_16x16x32_bf16(a, b, acc[nt], 0, 0, 0);
        }
    }
    #pragma unroll
    for (int nt = 0; nt < NT; ++nt) {
        int col = n0 + nt * 16 + l16;
        float bv = (bias != nullptr) ? bias[col] : 0.f;
        #pragma unroll
        for (int r = 0; r < 4; ++r) {
            int row = m0 + quad * 4 + r;
            if (outF != nullptr) outF[(size_t)row * 512 + col] = acc[nt][r] + bv;
            else                 outB[(size_t)row * 512 + col] = f2bf(acc[nt][r]);
        }
    }
}

// ---- K2: fused qkv GEMM (128x192x512) + window attention ------------------
// grid (392, 8): blockIdx.x = 128-token block (8 windows), blockIdx.y = head.
__global__ void __launch_bounds__(256) k_fused(const unsigned short* __restrict__ XW,
                                               const unsigned short* __restrict__ WH,
                                               unsigned short* __restrict__ XH) {
    __shared__ __align__(16) char smem[63744];
    unsigned short* As  = (unsigned short*)smem;             // [128][32]  8192 B (stage)
    unsigned short* Bs  = (unsigned short*)(smem + 8192);    // [192][32] 12288 B (stage)
    unsigned short* qs  = (unsigned short*)smem;             // [128][72] 18432 B (attn)
    unsigned short* ks  = (unsigned short*)(smem + 18432);   // [128][72]
    unsigned short* vts = (unsigned short*)(smem + 36864);   // [64][144] (v^T, tok-padded)
    float*          Ss  = (float*)(smem + 55296);            // [4][16][17] f32
    unsigned short* Ps  = (unsigned short*)(smem + 59648);   // [4][16][32]

    const int wave = threadIdx.x >> 6, lane = threadIdx.x & 63;
    const int quad = lane >> 4, l16 = lane & 15;
    const int head = blockIdx.y;
    const int m0   = blockIdx.x * 128;

    // staging source pointers (per-lane), advanced by 32 elems per K-iter
    const unsigned short* ap[2];
    #pragma unroll
    for (int i = 0; i < 2; ++i) {
        int q = (wave * 2 + i) * 64 + lane;
        ap[i] = XW + (size_t)(m0 + (q >> 2)) * 512 + (q & 3) * 8;
    }
    const unsigned short* bp[3];
    #pragma unroll
    for (int i = 0; i < 3; ++i) {
        int q = (wave * 3 + i) * 64 + lane;
        int r = q >> 2;                               // 0..191 (s-major qkv row)
        int nrow = (r >> 6) * 512 + head * 64 + (r & 63);
        bp[i] = WH + (size_t)nrow * 512 + (q & 3) * 8;
    }

    const int m_loc = (wave >> 1) * 64, n_loc = (wave & 1) * 96;
    f32x4 acc[4][6] = {};

    for (int it = 0; it < 16; ++it) {
        #pragma unroll
        for (int i = 0; i < 2; ++i)
            gl2lds16(ap[i] + it * 32, As + (wave * 2 + i) * 512);
        #pragma unroll
        for (int i = 0; i < 3; ++i)
            gl2lds16(bp[i] + it * 32, Bs + (wave * 3 + i) * 512);
        __syncthreads();
        bf16x8 af[4], bfv[6];
        #pragma unroll
        for (int i = 0; i < 4; ++i)
            af[i] = *(const bf16x8*)&As[(m_loc + i * 16 + l16) * 32 + quad * 8];
        #pragma unroll
        for (int j = 0; j < 6; ++j)
            bfv[j] = *(const bf16x8*)&Bs[(n_loc + j * 16 + l16) * 32 + quad * 8];
        #pragma unroll
        for (int i = 0; i < 4; ++i)
            #pragma unroll
            for (int j = 0; j < 6; ++j)
                acc[i][j] = __builtin_amdgcn_mfma_f32_16x16x32_bf16(af[i], bfv[j], acc[i][j], 0, 0, 0);
        __syncthreads();
    }

    // ---- scatter qkv C-tiles into attention LDS (overlaps stage region) ----
    #pragma unroll
    for (int j = 0; j < 6; ++j) {
        int ncol = n_loc + j * 16 + l16;       // 0..191
        int s = ncol >> 6, ch = ncol & 63;     // s uniform per j
        #pragma unroll
        for (int i = 0; i < 4; ++i)
            #pragma unroll
            for (int r = 0; r < 4; ++r) {
                int tok = m_loc + i * 16 + quad * 4 + r;
                unsigned short hv = f2bf(acc[i][j][r]);
                if (s == 0)      qs[tok * 72 + ch] = hv;
                else if (s == 1) ks[tok * 72 + ch] = hv;
                else             vts[ch * 144 + tok] = hv;
            }
    }
    // zero pads: vts cols 128..143, Ps cols 16..31
    for (int idx = threadIdx.x; idx < 64 * 16; idx += 256)
        vts[(idx >> 4) * 144 + 128 + (idx & 15)] = 0;
    for (int idx = threadIdx.x; idx < 1024; idx += 256)
        Ps[(idx >> 4) * 32 + 16 + (idx & 15)] = 0;
    __syncthreads();

    // ---- attention: wave handles windows wave*2 and wave*2+1 ---------------
    #pragma unroll
    for (int wi2 = 0; wi2 < 2; ++wi2) {
        const int t0 = (wave * 2 + wi2) * 16;
        f32x4 sacc = {};
        {
            bf16x8 a0 = *(const bf16x8*)&qs[(t0 + l16) * 72 + quad * 8];
            bf16x8 b0 = *(const bf16x8*)&ks[(t0 + l16) * 72 + quad * 8];
            sacc = __builtin_amdgcn_mfma_f32_16x16x32_bf16(a0, b0, sacc, 0, 0, 0);
            bf16x8 a1 = *(const bf16x8*)&qs[(t0 + l16) * 72 + 32 + quad * 8];
            bf16x8 b1 = *(const bf16x8*)&ks[(t0 + l16) * 72 + 32 + quad * 8];
            sacc = __builtin_amdgcn_mfma_f32_16x16x32_bf16(a1, b1, sacc, 0, 0, 0);
        }
        #pragma unroll
        for (int r = 0; r < 4; ++r)
            Ss[wave * 272 + (quad * 4 + r) * 17 + l16] = sacc[r] * SCALE;
        __syncthreads();
        if (lane < 16) {
            float vals[16], m = -1e30f;
            #pragma unroll
            for (int c = 0; c < 16; ++c) { vals[c] = Ss[wave * 272 + lane * 17 + c]; m = fmaxf(m, vals[c]); }
            float sum = 0.f;
            #pragma unroll
            for (int c = 0; c < 16; ++c) { vals[c] = __expf(vals[c] - m); sum += vals[c]; }
            float inv = 1.f / sum;
            #pragma unroll
            for (int c = 0; c < 16; ++c) Ps[wave * 512 + lane * 32 + c] = f2bf(vals[c] * inv);
        }
        __syncthreads();
        bf16x8 pa = *(const bf16x8*)&Ps[wave * 512 + l16 * 32 + quad * 8];
        #pragma unroll
        for (int nt = 0; nt < 4; ++nt) {
            f32x4 y = {};
            bf16x8 bv = *(const bf16x8*)&vts[(nt * 16 + l16) * 144 + t0 + quad * 8];
            y = __builtin_amdgcn_mfma_f32_16x16x32_bf16(pa, bv, y, 0, 0, 0);
            #pragma unroll
            for (int r = 0; r < 4; ++r)
                XH[(size_t)(m0 + t0 + quad * 4 + r) * 512 + head * 64 + nt * 16 + l16] = f2bf(y[r]);
        }
    }
}

// ---- K3: out = XH @ WP1^T + G[win], window-reverse scatter (m97 GEMM) -----
// grid (392, 4)
__global__ void __launch_bounds__(256) k_gemm_proj(const unsigned short* __restrict__ XH,
                                                   const unsigned short* __restrict__ WP1,
                                                   const float* __restrict__ G,
                                                   float* __restrict__ out) {
    __shared__ __align__(16) unsigned short As[4096];   // [128][32]
    __shared__ __align__(16) unsigned short Bs[4096];   // [128][32]

    const int wave = threadIdx.x >> 6, lane = threadIdx.x & 63;
    const int quad = lane >> 4, l16 = lane & 15;
    const int m0 = blockIdx.x * 128, n0 = blockIdx.y * 128;

    const unsigned short* ap[2];
    const unsigned short* bp[2];
    #pragma unroll
    for (int i = 0; i < 2; ++i) {
        int q = (wave * 2 + i) * 64 + lane;
        ap[i] = XH  + (size_t)(m0 + (q >> 2)) * 512 + (q & 3) * 8;
        bp[i] = WP1 + (size_t)(n0 + (q >> 2)) * 512 + (q & 3) * 8;
    }

    const int m_loc = (wave >> 1) * 64, n_loc = (wave & 1) * 64;
    f32x4 acc[4][4] = {};

    for (int it = 0; it < 16; ++it) {
        #pragma unroll
        for (int i = 0; i < 2; ++i) {
            gl2lds16(ap[i] + it * 32, As + (wave * 2 + i) * 512);
            gl2lds16(bp[i] + it * 32, Bs + (wave * 2 + i) * 512);
        }
        __syncthreads();
        bf16x8 af[4], bfv[4];
        #pragma unroll
        for (int i = 0; i < 4; ++i) {
            af[i]  = *(const bf16x8*)&As[(m_loc + i * 16 + l16) * 32 + quad * 8];
            bfv[i] = *(const bf16x8*)&Bs[(n_loc + i * 16 + l16) * 32 + quad * 8];
        }
        #pragma unroll
        for (int i = 0; i < 4; ++i)
            #pragma unroll
            for (int j = 0; j < 4; ++j)
                acc[i][j] = __builtin_amdgcn_mfma_f32_16x16x32_bf16(af[i], bfv[j], acc[i][j], 0, 0, 0);
        __syncthreads();
    }

    #pragma unroll
    for (int i = 0; i < 4; ++i)
        #pragma unroll
        for (int r = 0; r < 4; ++r) {
            int mm = m0 + m_loc + i * 16 + quad * 4 + r;
            int win = mm >> 4, tok = mm & 15;
            int bb = win / 196, rem = win % 196;
            int wh = rem / 14, ww = rem % 14;
            int orow = (bb * 56 + wh * 4 + (tok >> 2)) * 56 + ww * 4 + (tok & 3);
            #pragma unroll
            for (int j = 0; j < 4; ++j) {
                int ncol = n0 + n_loc + j * 16 + l16;
                out[(size_t)orow * 512 + ncol] = acc[i][j][r] + G[(size_t)win * 512 + ncol];
            }
        }
}

// ---------------------------------------------------------------------------
extern "C" void kernel_launch(void* const* d_in, const int* in_sizes, int n_in,
                              void* d_out, int out_size, void* d_ws, size_t ws_size,
                              hipStream_t stream) {
    const float* x      = (const float*)d_in[0];
    const float* wqkv_h = (const float*)d_in[1];
    const float* wqkv_l = (const float*)d_in[2];
    const float* wproj  = (const float*)d_in[3];
    const float* bproj  = (const float*)d_in[4];
    float* out = (float*)d_out;

    char* ws = (char*)d_ws;
    unsigned short* WH   = (unsigned short*)(ws + 0);         // 1536*512 bf16
    unsigned short* WLV  = (unsigned short*)(ws + 1572864);   // 512*512
    unsigned short* WP1  = (unsigned short*)(ws + 2097152);   // 512*512
    unsigned short* WP2  = (unsigned short*)(ws + 2621440);   // 512*512
    unsigned short* XW   = (unsigned short*)(ws + 3145728);   // 50176*512
    unsigned short* XAVG = (unsigned short*)(ws + 54525952);  // 3136*512
    unsigned short* VL   = (unsigned short*)(ws + 57737216);  // 3136*512
    float*          G    = (float*)(ws + 60948480);           // 3136*512 f32
    unsigned short* XH   = (unsigned short*)(ws + 67371008);  // 50176*512

    k_prep_weights<<<dim3(6144), dim3(256), 0, stream>>>(wqkv_h, wqkv_l, wproj, WH, WLV, WP1, WP2);
    k_window_pool<<<dim3(3136), dim3(256), 0, stream>>>(x, XW, XAVG);
    k_gemm512<2><<<dim3(49, 16), dim3(256), 0, stream>>>(XAVG, WLV, VL, (float*)nullptr, (const float*)nullptr);
    k_gemm512<2><<<dim3(49, 16), dim3(256), 0, stream>>>(VL, WP2, (unsigned short*)nullptr, G, bproj);
    k_fused<<<dim3(392, 8), dim3(256), 0, stream>>>(XW, WH, XH);
    k_gemm_proj<<<dim3(392, 4), dim3(256), 0, stream>>>(XH, WP1, G, out);
}

// Round 3
// 420.455 us; speedup vs baseline: 2.5049x; 1.2841x over previous
//
#include <hip/hip_runtime.h>

// ---------------------------------------------------------------------------
// SpatialAwareSelfAttention  (B=16, H=W=56, C=512, heads=8, window=4x4)
//
// Round 3: occupancy-first fused kernel.
//   k_fused: block = 64 tokens (4 windows) x 1 head. 64x192x512 GEMM with
//   global_load_lds staging (33.8KB LDS total, 4 blocks/CU), in-register
//   quad-shuffle softmax, per-wave barrier-free attention.
//   k_gemm_proj: 64x128 tiles, 12KB LDS.
// ---------------------------------------------------------------------------

using bf16x8 = __attribute__((ext_vector_type(8))) short;
using f32x4  = __attribute__((ext_vector_type(4))) float;

#define SCALE 0.044194173824159216f   // 512^-0.5 (full C, per reference)

__device__ __forceinline__ unsigned short f2bf(float f) {
    union { float f; unsigned u; } v; v.f = f;
    unsigned u = v.u;
    return (unsigned short)((u + 0x7fffu + ((u >> 16) & 1u)) >> 16);
}

__device__ __forceinline__ void gl2lds16(const unsigned short* g, unsigned short* l) {
    __builtin_amdgcn_global_load_lds(
        (const __attribute__((address_space(1))) void*)g,
        (__attribute__((address_space(3))) void*)l, 16, 0, 0);
}

// ---- K0a: weight conversion/repack ----------------------------------------
__global__ void k_prep_weights(const float* __restrict__ wqkv_h,
                               const float* __restrict__ wqkv_l,
                               const float* __restrict__ wproj,
                               unsigned short* __restrict__ WH,
                               unsigned short* __restrict__ WLV,
                               unsigned short* __restrict__ WP1,
                               unsigned short* __restrict__ WP2) {
    int i = blockIdx.x * 256 + threadIdx.x;
    if (i < 786432) {
        WH[i] = f2bf(wqkv_h[i]);              // [1536][512] row-major
    } else {
        int j = i - 786432;
        int r = j >> 18;
        int t = j & 262143;
        int n = t >> 9, k = t & 511;
        if (r == 0)      WLV[t] = f2bf(wqkv_l[(1024 + n) * 512 + k]); // v-rows
        else if (r == 1) WP1[t] = f2bf(wproj[n * 1024 + k]);
        else             WP2[t] = f2bf(wproj[n * 1024 + 512 + k]);
    }
}

// ---- K0b: window partition + pooling (float4 / ushort4) -------------------
__global__ void k_window_pool(const float* __restrict__ x,
                              unsigned short* __restrict__ XW,
                              unsigned short* __restrict__ XAVG) {
    int win = blockIdx.x * 2 + (threadIdx.x >> 7);
    int g = threadIdx.x & 127;
    int c = g * 4;
    int b = win / 196, rem = win % 196, wh = rem / 14, ww = rem % 14;
    float4 s = {0.f, 0.f, 0.f, 0.f};
    #pragma unroll
    for (int t = 0; t < 16; ++t) {
        int row = (b * 56 + wh * 4 + (t >> 2)) * 56 + ww * 4 + (t & 3);
        float4 v = *(const float4*)&x[(size_t)row * 512 + c];
        uint2 pk;
        pk.x = (unsigned)f2bf(v.x) | ((unsigned)f2bf(v.y) << 16);
        pk.y = (unsigned)f2bf(v.z) | ((unsigned)f2bf(v.w) << 16);
        *(uint2*)&XW[(size_t)(win * 16 + t) * 512 + c] = pk;
        s.x += v.x; s.y += v.y; s.z += v.z; s.w += v.w;
    }
    uint2 pa;
    pa.x = (unsigned)f2bf(s.x * 0.0625f) | ((unsigned)f2bf(s.y * 0.0625f) << 16);
    pa.y = (unsigned)f2bf(s.z * 0.0625f) | ((unsigned)f2bf(s.w * 0.0625f) << 16);
    *(uint2*)&XAVG[(size_t)win * 512 + c] = pa;
}

// ---- K1: small K=512 GEMM C = A @ B^T, wave tile 16 x (NT*16) -------------
template <int NT>
__global__ void k_gemm512(const unsigned short* __restrict__ A,
                          const unsigned short* __restrict__ Bw,
                          unsigned short* __restrict__ outB,
                          float* __restrict__ outF,
                          const float* __restrict__ bias) {
    int wave = threadIdx.x >> 6, lane = threadIdx.x & 63;
    int quad = lane >> 4, l16 = lane & 15;
    int m0 = blockIdx.x * 64 + wave * 16;
    int n0 = blockIdx.y * (NT * 16);
    f32x4 acc[NT] = {};
    const unsigned short* arow = A + (size_t)(m0 + l16) * 512 + quad * 8;
    for (int kk = 0; kk < 16; ++kk) {
        bf16x8 a = *(const bf16x8*)(arow + kk * 32);
        #pragma unroll
        for (int nt = 0; nt < NT; ++nt) {
            bf16x8 b = *(const bf16x8*)(Bw + (size_t)(n0 + nt * 16 + l16) * 512 + kk * 32 + quad * 8);
            acc[nt] = __builtin_amdgcn_mfma_f32_16x16x32_bf16(a, b, acc[nt], 0, 0, 0);
        }
    }
    #pragma unroll
    for (int nt = 0; nt < NT; ++nt) {
        int col = n0 + nt * 16 + l16;
        float bv = (bias != nullptr) ? bias[col] : 0.f;
        #pragma unroll
        for (int r = 0; r < 4; ++r) {
            int row = m0 + quad * 4 + r;
            if (outF != nullptr) outF[(size_t)row * 512 + col] = acc[nt][r] + bv;
            else                 outB[(size_t)row * 512 + col] = f2bf(acc[nt][r]);
        }
    }
}

// ---- K2: fused qkv GEMM (64x192x512) + window attention -------------------
// grid (784, 8): blockIdx.x = 64-token block (4 windows), blockIdx.y = head.
// wave w owns window w of the block (tokens w*16..w*16+15).
__global__ void __launch_bounds__(256, 4) k_fused(const unsigned short* __restrict__ XW,
                                                  const unsigned short* __restrict__ WH,
                                                  unsigned short* __restrict__ XH) {
    __shared__ __align__(16) char smem[33792];
    // staging union (dead after K-loop):
    unsigned short* As  = (unsigned short*)smem;             // [64][32]   4096 B
    unsigned short* Bs  = (unsigned short*)(smem + 4096);    // [192][32] 12288 B
    // attention region:
    unsigned short* qs  = (unsigned short*)smem;             // [64][72]   9216 B
    unsigned short* ks  = (unsigned short*)(smem + 9216);    // [64][72]   9216 B
    unsigned short* vts = (unsigned short*)(smem + 18432);   // [64][88]  11264 B (ch x tok)
    unsigned short* Ps  = (unsigned short*)(smem + 29696);   // [4][16][32] 4096 B

    const int wave = threadIdx.x >> 6, lane = threadIdx.x & 63;
    const int quad = lane >> 4, l16 = lane & 15;
    const int head = blockIdx.y;
    const int m0   = blockIdx.x * 64;

    // staging source pointers
    const unsigned short* ap;
    {
        int q = wave * 64 + lane;
        ap = XW + (size_t)(m0 + (q >> 2)) * 512 + (q & 3) * 8;
    }
    const unsigned short* bp[3];
    #pragma unroll
    for (int i = 0; i < 3; ++i) {
        int q = (wave * 3 + i) * 64 + lane;
        int r = q >> 2;                               // 0..191 (s-major qkv row)
        int nrow = (r >> 6) * 512 + head * 64 + (r & 63);
        bp[i] = WH + (size_t)nrow * 512 + (q & 3) * 8;
    }

    f32x4 acc[12] = {};   // wave tile: rows wave*16..+15, cols 0..191

    for (int it = 0; it < 16; ++it) {
        gl2lds16(ap + it * 32, As + wave * 512);
        #pragma unroll
        for (int i = 0; i < 3; ++i)
            gl2lds16(bp[i] + it * 32, Bs + (wave * 3 + i) * 512);
        __syncthreads();
        bf16x8 af = *(const bf16x8*)&As[(wave * 16 + l16) * 32 + quad * 8];
        #pragma unroll
        for (int j = 0; j < 12; ++j) {
            bf16x8 b = *(const bf16x8*)&Bs[(j * 16 + l16) * 32 + quad * 8];
            acc[j] = __builtin_amdgcn_mfma_f32_16x16x32_bf16(af, b, acc[j], 0, 0, 0);
        }
        __syncthreads();   // guards stage overwrite AND (last iter) attn-scatter
    }

    // ---- scatter q/k/v^T into attention LDS (aliases stage region) --------
    #pragma unroll
    for (int j = 0; j < 12; ++j) {
        #pragma unroll
        for (int r = 0; r < 4; ++r) {
            int tok = wave * 16 + quad * 4 + r;       // block-local token
            unsigned short hv = f2bf(acc[j][r]);
            if (j < 4)        qs[tok * 72 + j * 16 + l16] = hv;
            else if (j < 8)   ks[tok * 72 + (j - 4) * 16 + l16] = hv;
            else              vts[((j - 8) * 16 + l16) * 88 + tok] = hv;
        }
    }
    // zero pads: vts token-cols 64..79 (read by wave 3's PV), Ps cols 16..31
    if (wave == 3) {
        #pragma unroll
        for (int i = 0; i < 16; ++i) vts[lane * 88 + 64 + i] = 0;
    }
    {
        int prow = lane >> 2, pc = 16 + (lane & 3) * 4;
        #pragma unroll
        for (int i = 0; i < 4; ++i) Ps[wave * 512 + prow * 32 + pc + i] = 0;
    }
    // NOTE: no __syncthreads needed — each wave reads only its own window's
    // qs/ks/vts/Ps rows (PV's K-padding taps into neighbor data but P=0 there).

    // ---- S = (q @ k^T) * scale --------------------------------------------
    const int t0 = wave * 16;
    f32x4 sacc = {};
    {
        bf16x8 a0 = *(const bf16x8*)&qs[(t0 + l16) * 72 + quad * 8];
        bf16x8 b0 = *(const bf16x8*)&ks[(t0 + l16) * 72 + quad * 8];
        sacc = __builtin_amdgcn_mfma_f32_16x16x32_bf16(a0, b0, sacc, 0, 0, 0);
        bf16x8 a1 = *(const bf16x8*)&qs[(t0 + l16) * 72 + 32 + quad * 8];
        bf16x8 b1 = *(const bf16x8*)&ks[(t0 + l16) * 72 + 32 + quad * 8];
        sacc = __builtin_amdgcn_mfma_f32_16x16x32_bf16(a1, b1, sacc, 0, 0, 0);
    }
    // ---- in-register softmax: row r lives across the quad's 16 lanes ------
    float p[4];
    #pragma unroll
    for (int r = 0; r < 4; ++r) {
        float v = sacc[r] * SCALE;
        float m = v;
        m = fmaxf(m, __shfl_xor(m, 1));
        m = fmaxf(m, __shfl_xor(m, 2));
        m = fmaxf(m, __shfl_xor(m, 4));
        m = fmaxf(m, __shfl_xor(m, 8));
        float e = __expf(v - m);
        float s = e;
        s += __shfl_xor(s, 1);
        s += __shfl_xor(s, 2);
        s += __shfl_xor(s, 4);
        s += __shfl_xor(s, 8);
        p[r] = e / s;
    }
    #pragma unroll
    for (int r = 0; r < 4; ++r)
        Ps[wave * 512 + (quad * 4 + r) * 32 + l16] = f2bf(p[r]);

    // ---- y = P @ v (K=16 padded to 32; pad-P is zero) ---------------------
    bf16x8 pa = *(const bf16x8*)&Ps[wave * 512 + l16 * 32 + quad * 8];
    #pragma unroll
    for (int nt = 0; nt < 4; ++nt) {
        f32x4 y = {};
        bf16x8 bv = *(const bf16x8*)&vts[(nt * 16 + l16) * 88 + t0 + quad * 8];
        y = __builtin_amdgcn_mfma_f32_16x16x32_bf16(pa, bv, y, 0, 0, 0);
        #pragma unroll
        for (int r = 0; r < 4; ++r)
            XH[(size_t)(m0 + t0 + quad * 4 + r) * 512 + head * 64 + nt * 16 + l16] = f2bf(y[r]);
    }
}

// ---- K3: out = XH @ WP1^T + G[win], 64x128 tiles, scatter epilogue --------
// grid (784, 4)
__global__ void __launch_bounds__(256, 4) k_gemm_proj(const unsigned short* __restrict__ XH,
                                                      const unsigned short* __restrict__ WP1,
                                                      const float* __restrict__ G,
                                                      float* __restrict__ out) {
    __shared__ __align__(16) unsigned short As[2048];   // [64][32]   4096 B
    __shared__ __align__(16) unsigned short Bs[4096];   // [128][32]  8192 B

    const int wave = threadIdx.x >> 6, lane = threadIdx.x & 63;
    const int quad = lane >> 4, l16 = lane & 15;
    const int m0 = blockIdx.x * 64, n0 = blockIdx.y * 128;

    const unsigned short* ap;
    {
        int q = wave * 64 + lane;
        ap = XH + (size_t)(m0 + (q >> 2)) * 512 + (q & 3) * 8;
    }
    const unsigned short* bp[2];
    #pragma unroll
    for (int i = 0; i < 2; ++i) {
        int q = (wave * 2 + i) * 64 + lane;
        bp[i] = WP1 + (size_t)(n0 + (q >> 2)) * 512 + (q & 3) * 8;
    }

    f32x4 acc[8] = {};    // wave tile: rows wave*16..+15, cols n0..n0+127

    for (int it = 0; it < 16; ++it) {
        gl2lds16(ap + it * 32, As + wave * 512);
        #pragma unroll
        for (int i = 0; i < 2; ++i)
            gl2lds16(bp[i] + it * 32, Bs + (wave * 2 + i) * 512);
        __syncthreads();
        bf16x8 af = *(const bf16x8*)&As[(wave * 16 + l16) * 32 + quad * 8];
        #pragma unroll
        for (int j = 0; j < 8; ++j) {
            bf16x8 b = *(const bf16x8*)&Bs[(j * 16 + l16) * 32 + quad * 8];
            acc[j] = __builtin_amdgcn_mfma_f32_16x16x32_bf16(af, b, acc[j], 0, 0, 0);
        }
        __syncthreads();
    }

    int win = blockIdx.x * 4 + wave;
    int bb = win / 196, rem = win % 196;
    int wh = rem / 14, ww = rem % 14;
    #pragma unroll
    for (int r = 0; r < 4; ++r) {
        int tok = quad * 4 + r;
        int orow = (bb * 56 + wh * 4 + (tok >> 2)) * 56 + ww * 4 + (tok & 3);
        #pragma unroll
        for (int j = 0; j < 8; ++j) {
            int ncol = n0 + j * 16 + l16;
            out[(size_t)orow * 512 + ncol] = acc[j][r] + G[(size_t)win * 512 + ncol];
        }
    }
}

// ---------------------------------------------------------------------------
extern "C" void kernel_launch(void* const* d_in, const int* in_sizes, int n_in,
                              void* d_out, int out_size, void* d_ws, size_t ws_size,
                              hipStream_t stream) {
    const float* x      = (const float*)d_in[0];
    const float* wqkv_h = (const float*)d_in[1];
    const float* wqkv_l = (const float*)d_in[2];
    const float* wproj  = (const float*)d_in[3];
    const float* bproj  = (const float*)d_in[4];
    float* out = (float*)d_out;

    char* ws = (char*)d_ws;
    unsigned short* WH   = (unsigned short*)(ws + 0);         // 1536*512 bf16
    unsigned short* WLV  = (unsigned short*)(ws + 1572864);   // 512*512
    unsigned short* WP1  = (unsigned short*)(ws + 2097152);   // 512*512
    unsigned short* WP2  = (unsigned short*)(ws + 2621440);   // 512*512
    unsigned short* XW   = (unsigned short*)(ws + 3145728);   // 50176*512
    unsigned short* XAVG = (unsigned short*)(ws + 54525952);  // 3136*512
    unsigned short* VL   = (unsigned short*)(ws + 57737216);  // 3136*512
    float*          G    = (float*)(ws + 60948480);           // 3136*512 f32
    unsigned short* XH   = (unsigned short*)(ws + 67371008);  // 50176*512

    k_prep_weights<<<dim3(6144), dim3(256), 0, stream>>>(wqkv_h, wqkv_l, wproj, WH, WLV, WP1, WP2);
    k_window_pool<<<dim3(1568), dim3(256), 0, stream>>>(x, XW, XAVG);
    k_gemm512<2><<<dim3(49, 16), dim3(256), 0, stream>>>(XAVG, WLV, VL, (float*)nullptr, (const float*)nullptr);
    k_gemm512<2><<<dim3(49, 16), dim3(256), 0, stream>>>(VL, WP2, (unsigned short*)nullptr, G, bproj);
    k_fused<<<dim3(784, 8), dim3(256), 0, stream>>>(XW, WH, XH);
    k_gemm_proj<<<dim3(784, 4), dim3(256), 0, stream>>>(XH, WP1, G, out);
}